// Round 2
// baseline (158.107 us; speedup 1.0000x reference)
//
#include <hip/hip_runtime.h>

#define NB     1024      // systems
#define NDOF   64        // dof per system
#define NSTEPS 200
#define DTF    0.002f

// One wave (64 lanes) per system; lane == dof index.
// Per step: 2 expf + 1 butterfly KE-reduction (the trailing KE of step n is
// the opening KE of step n+1; the reference's other KE/G recomputes are dead).
__global__ __launch_bounds__(256) void nhc_kernel(
    const float* __restrict__ x0, const float* __restrict__ v0,
    const float* __restrict__ kTp, const float* __restrict__ massp,
    const float* __restrict__ Qp, float* __restrict__ out)
{
    const int tid  = blockIdx.x * blockDim.x + threadIdx.x;
    const int sys  = tid >> 6;
    const int lane = tid & 63;
    if (sys >= NB) return;

    const float kT   = kTp[0];
    const float mass = massp[0];
    const float Q    = Qp[0];

    const float dt   = DTF;
    const float dt2  = 0.5f   * DTF;
    const float dt4  = 0.25f  * DTF;
    const float dt8  = 0.125f * DTF;
    const float invQ = 1.0f / Q;
    const float c    = dt2 / mass;      // verlet half-kick coefficient (F=-x)

    float x = x0[sys * NDOF + lane];
    float v = v0[sys * NDOF + lane];
    float xi0 = 0.0f, xi1 = 0.0f;

    float* __restrict__ out_x = out;
    float* __restrict__ out_v = out + (size_t)(NSTEPS + 1) * NB * NDOF;

    // step-0 snapshot
    out_x[sys * NDOF + lane] = x;
    out_v[sys * NDOF + lane] = v;

    // initial KE = 0.5*mass*sum(v^2)
    float vv = v * v;
    #pragma unroll
    for (int off = 32; off; off >>= 1) vv += __shfl_xor(vv, off, 64);
    float KE = 0.5f * mass * vv;

    size_t widx = (size_t)NB * NDOF + sys * NDOF + lane;  // step-1 slot

    for (int n = 0; n < NSTEPS; ++n) {
        // ---- first half chain (j = 1, then j = 0) ----
        float G = (2.0f * KE - (float)NDOF * kT) * invQ;
        xi1 = xi1 + dt4 * G;
        G = (Q * xi0 * xi0 - kT) * invQ;
        float s = __expf(-xi1 * dt8);           // xi1 already updated
        xi0 = (xi0 * s + dt4 * G) * s;
        float sc = __expf(-xi0 * dt2);          // xi0 already updated
        v *= sc;
        // (reference recomputes KE,G here -> dead, overwritten after verlet)

        // ---- velocity Verlet, F = -x ----
        v = v - c * x;
        x = x + dt * v;
        v = v - c * x;
        // (reference's post-verlet KE,G -> dead, overwritten in 2nd half j=0)

        // ---- second half chain (j = 0, then j = 1) ----
        v *= sc;                                 // same xi0 -> same scale
        vv = v * v;
        #pragma unroll
        for (int off = 32; off; off >>= 1) vv += __shfl_xor(vv, off, 64);
        KE = 0.5f * mass * vv;                   // reused as next step's KE
        G = (2.0f * KE - (float)NDOF * kT) * invQ;
        // s = exp(-xi1*dt/8): xi1 unchanged since first half -> reuse s
        xi0 = (xi0 * s + dt4 * G) * s;
        G = (Q * xi0 * xi0 - kT) * invQ;
        xi1 = xi1 + dt4 * G;
        // (reference's final G -> dead)

        out_x[widx] = x;
        out_v[widx] = v;
        widx += (size_t)NB * NDOF;
    }
}

extern "C" void kernel_launch(void* const* d_in, const int* in_sizes, int n_in,
                              void* d_out, int out_size, void* d_ws, size_t ws_size,
                              hipStream_t stream) {
    const float* x0   = (const float*)d_in[0];
    const float* v0   = (const float*)d_in[1];
    const float* kT   = (const float*)d_in[2];
    const float* mass = (const float*)d_in[3];
    const float* Q    = (const float*)d_in[4];
    float* out = (float*)d_out;

    const int total  = NB * NDOF;          // 65536 threads
    const int block  = 256;
    const int grid   = total / block;      // 256 blocks
    nhc_kernel<<<grid, block, 0, stream>>>(x0, v0, kT, mass, Q, out);
}

// Round 3
// 123.680 us; speedup vs baseline: 1.2784x; 1.2784x over previous
//
#include <hip/hip_runtime.h>

#define NB     1024      // systems
#define NDOF   64        // dof per system
#define NSTEPS 200
#define DTF    0.002f

// One wave (64 lanes) per system; lane == dof index.
// KE is tracked via wave-uniform second moments (Sxx, Sxv, Svv) which evolve
// under the same per-step linear maps as (x,v) -> NO per-step cross-lane
// reduction. Only a one-time butterfly at t=0 seeds the moments.
__global__ __launch_bounds__(256) void nhc_kernel(
    const float* __restrict__ x0, const float* __restrict__ v0,
    const float* __restrict__ kTp, const float* __restrict__ massp,
    const float* __restrict__ Qp, float* __restrict__ out)
{
    const int tid  = blockIdx.x * blockDim.x + threadIdx.x;
    const int sys  = tid >> 6;
    const int lane = tid & 63;
    if (sys >= NB) return;

    const float kT   = kTp[0];
    const float mass = massp[0];
    const float Q    = Qp[0];

    const float dt     = DTF;
    const float dt2    = 0.5f   * DTF;
    const float dt4    = 0.25f  * DTF;
    const float dt8    = 0.125f * DTF;
    const float invQ   = 1.0f / Q;
    const float c      = dt2 / mass;        // half-kick coeff (F = -x)
    const float c2     = c * c;
    const float dtdt   = dt * dt;
    const float ndofkT = (float)NDOF * kT;
    const float kTQ    = kT * invQ;         // used as (Q*xi^2 - kT)/Q literal below

    float x = x0[sys * NDOF + lane];
    float v = v0[sys * NDOF + lane];
    float xi0 = 0.0f, xi1 = 0.0f;

    float* __restrict__ out_x = out;
    float* __restrict__ out_v = out + (size_t)(NSTEPS + 1) * NB * NDOF;

    // step-0 snapshot
    out_x[sys * NDOF + lane] = x;
    out_v[sys * NDOF + lane] = v;

    // one-time moment seed: Sxx, Sxv, Svv (wave-uniform after butterflies)
    float Sxx = x * x, Sxv = x * v, Svv = v * v;
    #pragma unroll
    for (int off = 32; off; off >>= 1) {
        Sxx += __shfl_xor(Sxx, off, 64);
        Sxv += __shfl_xor(Sxv, off, 64);
        Svv += __shfl_xor(Svv, off, 64);
    }

    // Gk = (2*KE - ndof*kT)/Q with KE = 0.5*mass*Svv  (carried across steps:
    // the trailing KE of step n is the opening KE of step n+1)
    float Gk = (mass * Svv - ndofkT) * invQ;

    size_t widx = (size_t)NB * NDOF + sys * NDOF + lane;  // step-1 slot

    for (int n = 0; n < NSTEPS; ++n) {
        // ---- first half chain (j = 1, then j = 0) ----
        xi1 = fmaf(dt4, Gk, xi1);
        float s  = __expf(-xi1 * dt8);                 // xi1 already updated
        float G0 = fmaf(Q * xi0, xi0, -kT) * invQ;     // (Q*xi0^2 - kT)/Q, old xi0
        xi0 = fmaf(xi0, s, dt4 * G0) * s;
        float sc = __expf(-xi0 * dt2);                 // xi0 already updated
        float sc2 = sc * sc;

        // ---- per-dof trajectory update (only coupling to chain: sc) ----
        v *= sc;
        v = fmaf(-c, x, v);
        x = fmaf(dt, v, x);
        v = fmaf(-c, x, v);
        v *= sc;

        // ---- moment recursion (same linear maps, wave-uniform) ----
        Svv *= sc2;  Sxv *= sc;                        // first scaling
        float Svv1 = fmaf(c2, Sxx, fmaf(-2.0f * c, Sxv, Svv));   // kick 1
        float Sxv1 = fmaf(-c, Sxx, Sxv);
        float Sxx1 = fmaf(dtdt, Svv1, fmaf(2.0f * dt, Sxv1, Sxx)); // drift
        float Sxv2 = fmaf(dt, Svv1, Sxv1);
        float Svv2 = fmaf(c2, Sxx1, fmaf(-2.0f * c, Sxv2, Svv1)); // kick 2
        float Sxv3 = fmaf(-c, Sxx1, Sxv2);
        Svv = Svv2 * sc2;  Sxv = Sxv3 * sc;  Sxx = Sxx1;          // second scaling

        // ---- second half chain (j = 0, then j = 1) ----
        float Gt = (mass * Svv - ndofkT) * invQ;       // trailing-KE G
        xi0 = fmaf(xi0, s, dt4 * Gt) * s;              // same s (xi1 unchanged)
        float G1 = fmaf(Q * xi0, xi0, -kT) * invQ;
        xi1 = fmaf(dt4, G1, xi1);
        Gk = Gt;                                       // opening G of next step

        out_x[widx] = x;
        out_v[widx] = v;
        widx += (size_t)NB * NDOF;
    }
    (void)kTQ;
}

extern "C" void kernel_launch(void* const* d_in, const int* in_sizes, int n_in,
                              void* d_out, int out_size, void* d_ws, size_t ws_size,
                              hipStream_t stream) {
    const float* x0   = (const float*)d_in[0];
    const float* v0   = (const float*)d_in[1];
    const float* kT   = (const float*)d_in[2];
    const float* mass = (const float*)d_in[3];
    const float* Q    = (const float*)d_in[4];
    float* out = (float*)d_out;

    const int total = NB * NDOF;           // 65536 threads
    const int block = 256;
    const int grid  = total / block;       // 256 blocks -> 1 block/CU
    nhc_kernel<<<grid, block, 0, stream>>>(x0, v0, kT, mass, Q, out);
}